// Round 1
// baseline (4552.460 us; speedup 1.0000x reference)
//
#include <hip/hip_runtime.h>
#include <hip/hip_bf16.h>
#include <cstddef>

#define BB   2
#define CTX  1536
#define QQ   512
#define S_LEN 2048
#define DD   256
#define NH   8
#define DH   32
#define DFF  1024
#define NL   6
#define LIN  20
#define HOUTD 10

// ---------------- Embed: Z[b*S+s][d] ----------------
__global__ __launch_bounds__(256) void embed_k(
    const float* __restrict__ ctx_x, const float* __restrict__ ctx_z,
    const float* __restrict__ qry_x,
    const float* __restrict__ W_ctx, const float* __restrict__ b_ctx,
    const float* __restrict__ W_qry, const float* __restrict__ b_qry,
    float* __restrict__ Z)
{
    int row = blockIdx.x;            // 0..4095
    int d = threadIdx.x;             // 0..255
    int b = row >> 11, s = row & (S_LEN - 1);
    float acc;
    if (s < CTX) {
        const float* x1 = ctx_x + (size_t)(b * CTX + s) * LIN;
        const float* x2 = ctx_z + (size_t)(b * CTX + s) * HOUTD;
        const float* w = W_ctx + (size_t)d * (LIN + HOUTD);
        acc = b_ctx[d];
        #pragma unroll
        for (int i = 0; i < LIN; i++) acc += x1[i] * w[i];
        #pragma unroll
        for (int i = 0; i < HOUTD; i++) acc += x2[i] * w[LIN + i];
    } else {
        int qi = s - CTX;
        const float* x1 = qry_x + (size_t)(b * QQ + qi) * LIN;
        const float* w = W_qry + (size_t)d * (LIN + HOUTD);
        acc = b_qry[d];
        #pragma unroll
        for (int i = 0; i < LIN; i++) acc += x1[i] * w[i];
    }
    Z[(size_t)row * DD + d] = acc;
}

// ---------------- GEMM: Y[M,N] = X[M,K] @ W[N,K]^T + bias ----------------
// mode 0: plain   mode 1: relu   mode 2: scatter to Qt|Kt|Vt [B,NH,S,DH]
__global__ __launch_bounds__(256) void gemm_k(
    const float* __restrict__ X, const float* __restrict__ W,
    const float* __restrict__ bias, float* __restrict__ Y,
    int M, int N, int K, int mode)
{
    __shared__ float As[16][68];
    __shared__ float Bs[16][68];
    const int tid = threadIdx.x;
    const int bm = blockIdx.x << 6, bn = blockIdx.y << 6;
    const int lr = tid >> 2;            // 0..63
    const int lc = (tid & 3) << 2;      // 0,4,8,12
    const int ty = tid >> 4, tx = tid & 15;
    float c[4][4] = {};
    const float* Xp = X + (size_t)(bm + lr) * K + lc;
    const float* Wp = W + (size_t)(bn + lr) * K + lc;
    for (int k0 = 0; k0 < K; k0 += 16) {
        float4 xa = *(const float4*)(Xp + k0);
        float4 wb = *(const float4*)(Wp + k0);
        __syncthreads();
        As[lc + 0][lr] = xa.x; As[lc + 1][lr] = xa.y;
        As[lc + 2][lr] = xa.z; As[lc + 3][lr] = xa.w;
        Bs[lc + 0][lr] = wb.x; Bs[lc + 1][lr] = wb.y;
        Bs[lc + 2][lr] = wb.z; Bs[lc + 3][lr] = wb.w;
        __syncthreads();
        #pragma unroll
        for (int k = 0; k < 16; k++) {
            float4 a  = *(const float4*)&As[k][ty << 2];
            float4 bq = *(const float4*)&Bs[k][tx << 2];
            c[0][0] += a.x * bq.x; c[0][1] += a.x * bq.y; c[0][2] += a.x * bq.z; c[0][3] += a.x * bq.w;
            c[1][0] += a.y * bq.x; c[1][1] += a.y * bq.y; c[1][2] += a.y * bq.z; c[1][3] += a.y * bq.w;
            c[2][0] += a.z * bq.x; c[2][1] += a.z * bq.y; c[2][2] += a.z * bq.z; c[2][3] += a.z * bq.w;
            c[3][0] += a.w * bq.x; c[3][1] += a.w * bq.y; c[3][2] += a.w * bq.z; c[3][3] += a.w * bq.w;
        }
    }
    #pragma unroll
    for (int i = 0; i < 4; i++) {
        int mrow = bm + (ty << 2) + i;
        #pragma unroll
        for (int jj = 0; jj < 4; jj++) {
            int ncol = bn + (tx << 2) + jj;
            float v = c[i][jj] + bias[ncol];
            if (mode == 1) v = fmaxf(v, 0.0f);
            if (mode == 2) {
                int which = ncol >> 8, h = (ncol >> 5) & 7, d = ncol & 31;
                int bb = mrow >> 11, ss = mrow & (S_LEN - 1);
                Y[(size_t)which * (BB * NH * S_LEN * DH)
                  + ((size_t)((bb << 3) + h) * S_LEN + ss) * DH + d] = v;
            } else {
                Y[(size_t)mrow * N + ncol] = v;
            }
        }
    }
}

// ---------------- Attention ----------------
// grid: B*NH*(S/16) blocks; block 256 = 4 waves; each wave 4 query rows
__global__ __launch_bounds__(256) void attn_k(
    const float* __restrict__ Qt, const float* __restrict__ Kt,
    const float* __restrict__ Vt,
    const int* __restrict__ t_ctx, const int* __restrict__ t_qry,
    const float* __restrict__ alpha, float* __restrict__ O)
{
    const int bh = blockIdx.x >> 7;           // /(S/16)=128
    const int i0 = (blockIdx.x & 127) << 4;
    const int b = bh >> 3, h = bh & 7;
    const int tid = threadIdx.x;
    const int w = tid >> 6, lane = tid & 63;

    __shared__ float q_lds[16][32];
    __shared__ int ti_s[16];
    for (int idx = tid; idx < 16 * 32; idx += 256) {
        int r = idx >> 5, d = idx & 31;
        q_lds[r][d] = Qt[((size_t)bh * S_LEN + i0 + r) * DH + d];
    }
    if (tid < 16) {
        int i = i0 + tid;
        ti_s[tid] = (i < CTX) ? t_ctx[b * CTX + i] : t_qry[b * QQ + i - CTX];
    }
    __syncthreads();

    const float sc = 0.17677669529663687f;    // 1/sqrt(32)
    const float a_h = alpha[h];
    const int r0 = w << 2;
    int ti[4];
    #pragma unroll
    for (int r = 0; r < 4; r++) ti[r] = ti_s[r0 + r];

    float m[4], l[4];
    float4 acc[4][8];
    #pragma unroll
    for (int r = 0; r < 4; r++) {
        m[r] = -3.0e38f; l[r] = 0.0f;
        #pragma unroll
        for (int i = 0; i < 8; i++) acc[r][i] = make_float4(0.f, 0.f, 0.f, 0.f);
    }

    const float4* Kb = (const float4*)(Kt + (size_t)bh * S_LEN * DH);
    const float4* Vb = (const float4*)(Vt + (size_t)bh * S_LEN * DH);

    for (int j = lane; j < S_LEN; j += 64) {
        float4 kv4[8];
        const float4* kr = Kb + (size_t)j * 8;
        #pragma unroll
        for (int i = 0; i < 8; i++) kv4[i] = kr[i];
        int tj = (j < CTX) ? t_ctx[b * CTX + j] : t_qry[b * QQ + j - CTX];
        bool structok = (j < CTX);

        float s[4];
        #pragma unroll
        for (int r = 0; r < 4; r++) {
            const float4* q4 = (const float4*)q_lds[r0 + r];
            float ds = 0.0f;
            #pragma unroll
            for (int i = 0; i < 8; i++) {
                float4 qq = q4[i];
                ds += qq.x * kv4[i].x + qq.y * kv4[i].y + qq.z * kv4[i].z + qq.w * kv4[i].w;
            }
            bool ok = structok && (tj <= ti[r]);
            float dt = fabsf((float)(ti[r] - tj));
            s[r] = ok ? ds * sc - a_h * dt : -1e9f;
        }
        float p[4];
        #pragma unroll
        for (int r = 0; r < 4; r++) {
            if (s[r] > m[r]) {
                float f = __expf(m[r] - s[r]);
                m[r] = s[r]; l[r] *= f;
                #pragma unroll
                for (int i = 0; i < 8; i++) {
                    acc[r][i].x *= f; acc[r][i].y *= f; acc[r][i].z *= f; acc[r][i].w *= f;
                }
            }
            p[r] = __expf(s[r] - m[r]);
            l[r] += p[r];
        }
        const float4* vr = Vb + (size_t)j * 8;
        #pragma unroll
        for (int i = 0; i < 8; i++) kv4[i] = vr[i];
        #pragma unroll
        for (int r = 0; r < 4; r++) {
            #pragma unroll
            for (int i = 0; i < 8; i++) {
                acc[r][i].x += p[r] * kv4[i].x; acc[r][i].y += p[r] * kv4[i].y;
                acc[r][i].z += p[r] * kv4[i].z; acc[r][i].w += p[r] * kv4[i].w;
            }
        }
    }

    // merge across 64 lanes per row
    #pragma unroll
    for (int r = 0; r < 4; r++) {
        float mw = m[r];
        #pragma unroll
        for (int off = 32; off > 0; off >>= 1) mw = fmaxf(mw, __shfl_xor(mw, off, 64));
        float f = __expf(m[r] - mw);
        float lw = l[r] * f;
        #pragma unroll
        for (int off = 32; off > 0; off >>= 1) lw += __shfl_xor(lw, off, 64);
        float inv = 1.0f / lw;
        int d = lane & 31;
        float outv = 0.0f;
        #pragma unroll
        for (int i = 0; i < 8; i++) {
            float ax = acc[r][i].x * f, ay = acc[r][i].y * f;
            float az = acc[r][i].z * f, aw = acc[r][i].w * f;
            #pragma unroll
            for (int off = 32; off > 0; off >>= 1) {
                ax += __shfl_xor(ax, off, 64);
                ay += __shfl_xor(ay, off, 64);
                az += __shfl_xor(az, off, 64);
                aw += __shfl_xor(aw, off, 64);
            }
            if ((d >> 2) == i) {
                int dm = d & 3;
                outv = dm == 0 ? ax : dm == 1 ? ay : dm == 2 ? az : aw;
            }
        }
        if (lane < 32) {
            O[(size_t)(b * S_LEN + i0 + r0 + r) * DD + h * DH + d] = outv * inv;
        }
    }
}

// ---------------- Residual + LayerNorm (in-place on Z) ----------------
__global__ __launch_bounds__(256) void ln_k(
    float* __restrict__ Z, const float* __restrict__ Y,
    const float* __restrict__ sw, const float* __restrict__ bw)
{
    int row = blockIdx.x, t = threadIdx.x;
    float x = Z[(size_t)row * DD + t] + Y[(size_t)row * DD + t];
    float s1 = x, s2 = x * x;
    #pragma unroll
    for (int off = 32; off > 0; off >>= 1) {
        s1 += __shfl_xor(s1, off, 64);
        s2 += __shfl_xor(s2, off, 64);
    }
    __shared__ float ps1[4], ps2[4];
    int w = t >> 6, lane = t & 63;
    if (lane == 0) { ps1[w] = s1; ps2[w] = s2; }
    __syncthreads();
    float S1 = ps1[0] + ps1[1] + ps1[2] + ps1[3];
    float S2 = ps2[0] + ps2[1] + ps2[2] + ps2[3];
    float mu = S1 * (1.0f / DD);
    float var = S2 * (1.0f / DD) - mu * mu;
    float rs = rsqrtf(var + 1e-5f);
    Z[(size_t)row * DD + t] = (x - mu) * rs * sw[t] + bw[t];
}

// ---------------- Output head ----------------
__global__ __launch_bounds__(256) void outhead_k(
    const float* __restrict__ Z, const float* __restrict__ Wout,
    const float* __restrict__ bout, float* __restrict__ out)
{
    int tid = threadIdx.x;
    int rloc = tid >> 4, ho = tid & 15;
    int qrow = blockIdx.x * 16 + rloc;     // 0..1023
    int b = qrow >> 9, qi = qrow & (QQ - 1);
    if (ho < HOUTD) {
        const float* z = Z + (size_t)(b * S_LEN + CTX + qi) * DD;
        const float* wr = Wout + (size_t)ho * DD;
        float s = 0.0f;
        for (int d = 0; d < DD; d++) s += z[d] * wr[d];
        out[(size_t)(b * QQ + qi) * HOUTD + ho] = s + bout[ho];
    }
}

extern "C" void kernel_launch(void* const* d_in, const int* in_sizes, int n_in,
                              void* d_out, int out_size, void* d_ws, size_t ws_size,
                              hipStream_t stream) {
    (void)in_sizes; (void)n_in; (void)out_size; (void)ws_size;
    const float* ctx_x = (const float*)d_in[0];
    const float* ctx_z = (const float*)d_in[1];
    const float* qry_x = (const float*)d_in[2];
    const int* t_ctx = (const int*)d_in[3];
    const int* t_qry = (const int*)d_in[4];
    const float* W_ctx = (const float*)d_in[5];
    const float* b_ctx = (const float*)d_in[6];
    const float* W_qry = (const float*)d_in[7];
    const float* b_qry = (const float*)d_in[8];
    const float* alpha = (const float*)d_in[9];
    const float* Wqkv = (const float*)d_in[10];
    const float* bqkv = (const float*)d_in[11];
    const float* Wo = (const float*)d_in[12];
    const float* bo = (const float*)d_in[13];
    const float* ln1_s = (const float*)d_in[14];
    const float* ln1_b = (const float*)d_in[15];
    const float* W1 = (const float*)d_in[16];
    const float* b1 = (const float*)d_in[17];
    const float* W2 = (const float*)d_in[18];
    const float* b2 = (const float*)d_in[19];
    const float* ln2_s = (const float*)d_in[20];
    const float* ln2_b = (const float*)d_in[21];
    const float* W_out = (const float*)d_in[22];
    const float* b_out = (const float*)d_in[23];

    float* ws = (float*)d_ws;
    const size_t MTOT = (size_t)BB * S_LEN;       // 4096
    const size_t ZSZ = MTOT * DD;                 // 1M floats
    float* Z   = ws;
    float* QKV = ws + ZSZ;            // Qt|Kt|Vt, 3M floats
    float* AY  = ws + 4 * ZSZ;
    float* Yb  = ws + 5 * ZSZ;
    float* FF1 = ws + 6 * ZSZ;        // 4M floats

    embed_k<<<MTOT, 256, 0, stream>>>(ctx_x, ctx_z, qry_x, W_ctx, b_ctx, W_qry, b_qry, Z);

    for (int l = 0; l < NL; l++) {
        gemm_k<<<dim3(MTOT / 64, (3 * DD) / 64), 256, 0, stream>>>(
            Z, Wqkv + (size_t)l * 3 * DD * DD, bqkv + (size_t)l * 3 * DD, QKV,
            (int)MTOT, 3 * DD, DD, 2);
        attn_k<<<BB * NH * (S_LEN / 16), 256, 0, stream>>>(
            QKV, QKV + ZSZ, QKV + 2 * ZSZ, t_ctx, t_qry, alpha, AY);
        gemm_k<<<dim3(MTOT / 64, DD / 64), 256, 0, stream>>>(
            AY, Wo + (size_t)l * DD * DD, bo + (size_t)l * DD, Yb,
            (int)MTOT, DD, DD, 0);
        ln_k<<<MTOT, 256, 0, stream>>>(Z, Yb, ln1_s + (size_t)l * DD, ln1_b + (size_t)l * DD);
        gemm_k<<<dim3(MTOT / 64, DFF / 64), 256, 0, stream>>>(
            Z, W1 + (size_t)l * DFF * DD, b1 + (size_t)l * DFF, FF1,
            (int)MTOT, DFF, DD, 1);
        gemm_k<<<dim3(MTOT / 64, DD / 64), 256, 0, stream>>>(
            FF1, W2 + (size_t)l * DD * DFF, b2 + (size_t)l * DD, Yb,
            (int)MTOT, DD, DFF, 0);
        ln_k<<<MTOT, 256, 0, stream>>>(Z, Yb, ln2_s + (size_t)l * DD, ln2_b + (size_t)l * DD);
    }

    outhead_k<<<(BB * QQ) / 16, 256, 0, stream>>>(Z, W_out, b_out, (float*)d_out);
}

// Round 2
// 1230.136 us; speedup vs baseline: 3.7008x; 3.7008x over previous
//
#include <hip/hip_runtime.h>
#include <hip/hip_bf16.h>
#include <cstddef>

#define BB   2
#define CTX  1536
#define QQ   512
#define S_LEN 2048
#define DD   256
#define NH   8
#define DH   32
#define DFF  1024
#define NL   6
#define LIN  20
#define HOUTD 10

typedef _Float16 f16x4 __attribute__((ext_vector_type(4)));
typedef _Float16 f16x8 __attribute__((ext_vector_type(8)));
typedef float f32x4 __attribute__((ext_vector_type(4)));

// ---------------- t_all concat ----------------
__global__ __launch_bounds__(256) void tall_k(
    const int* __restrict__ t_ctx, const int* __restrict__ t_qry, int* __restrict__ t_all)
{
    int idx = blockIdx.x * 256 + threadIdx.x;     // 0..4095
    int b = idx >> 11, s = idx & (S_LEN - 1);
    t_all[idx] = (s < CTX) ? t_ctx[b * CTX + s] : t_qry[b * QQ + s - CTX];
}

// ---------------- Embed: Z[b*S+s][d] ----------------
__global__ __launch_bounds__(256) void embed_k(
    const float* __restrict__ ctx_x, const float* __restrict__ ctx_z,
    const float* __restrict__ qry_x,
    const float* __restrict__ W_ctx, const float* __restrict__ b_ctx,
    const float* __restrict__ W_qry, const float* __restrict__ b_qry,
    float* __restrict__ Z)
{
    int row = blockIdx.x;            // 0..4095
    int d = threadIdx.x;             // 0..255
    int b = row >> 11, s = row & (S_LEN - 1);
    float acc;
    if (s < CTX) {
        const float* x1 = ctx_x + (size_t)(b * CTX + s) * LIN;
        const float* x2 = ctx_z + (size_t)(b * CTX + s) * HOUTD;
        const float* w = W_ctx + (size_t)d * (LIN + HOUTD);
        acc = b_ctx[d];
        #pragma unroll
        for (int i = 0; i < LIN; i++) acc += x1[i] * w[i];
        #pragma unroll
        for (int i = 0; i < HOUTD; i++) acc += x2[i] * w[LIN + i];
    } else {
        int qi = s - CTX;
        const float* x1 = qry_x + (size_t)(b * QQ + qi) * LIN;
        const float* w = W_qry + (size_t)d * (LIN + HOUTD);
        acc = b_qry[d];
        #pragma unroll
        for (int i = 0; i < LIN; i++) acc += x1[i] * w[i];
    }
    Z[(size_t)row * DD + d] = acc;
}

// ---------------- GEMM: Y[M,N] = X[M,K] @ W[N,K]^T + bias ----------------
// mode 0: plain   mode 1: relu   mode 2: write f16 Q,K:[B,NH,S,DH] V:[B,NH,DH,S]
__global__ __launch_bounds__(256) void gemm_k(
    const float* __restrict__ X, const float* __restrict__ W,
    const float* __restrict__ bias, float* __restrict__ Y,
    int M, int N, int K, int mode,
    _Float16* __restrict__ Qh, _Float16* __restrict__ Kh, _Float16* __restrict__ Vh)
{
    __shared__ float As[16][68];
    __shared__ float Bs[16][68];
    const int tid = threadIdx.x;
    const int bm = blockIdx.x << 6, bn = blockIdx.y << 6;
    const int lr = tid >> 2;            // 0..63
    const int lc = (tid & 3) << 2;      // 0,4,8,12
    const int ty = tid >> 4, tx = tid & 15;
    float c[4][4] = {};
    const float* Xp = X + (size_t)(bm + lr) * K + lc;
    const float* Wp = W + (size_t)(bn + lr) * K + lc;
    for (int k0 = 0; k0 < K; k0 += 16) {
        float4 xa = *(const float4*)(Xp + k0);
        float4 wb = *(const float4*)(Wp + k0);
        __syncthreads();
        As[lc + 0][lr] = xa.x; As[lc + 1][lr] = xa.y;
        As[lc + 2][lr] = xa.z; As[lc + 3][lr] = xa.w;
        Bs[lc + 0][lr] = wb.x; Bs[lc + 1][lr] = wb.y;
        Bs[lc + 2][lr] = wb.z; Bs[lc + 3][lr] = wb.w;
        __syncthreads();
        #pragma unroll
        for (int k = 0; k < 16; k++) {
            float4 a  = *(const float4*)&As[k][ty << 2];
            float4 bq = *(const float4*)&Bs[k][tx << 2];
            c[0][0] += a.x * bq.x; c[0][1] += a.x * bq.y; c[0][2] += a.x * bq.z; c[0][3] += a.x * bq.w;
            c[1][0] += a.y * bq.x; c[1][1] += a.y * bq.y; c[1][2] += a.y * bq.z; c[1][3] += a.y * bq.w;
            c[2][0] += a.z * bq.x; c[2][1] += a.z * bq.y; c[2][2] += a.z * bq.z; c[2][3] += a.z * bq.w;
            c[3][0] += a.w * bq.x; c[3][1] += a.w * bq.y; c[3][2] += a.w * bq.z; c[3][3] += a.w * bq.w;
        }
    }
    #pragma unroll
    for (int i = 0; i < 4; i++) {
        int mrow = bm + (ty << 2) + i;
        #pragma unroll
        for (int jj = 0; jj < 4; jj++) {
            int ncol = bn + (tx << 2) + jj;
            float v = c[i][jj] + bias[ncol];
            if (mode == 1) v = fmaxf(v, 0.0f);
            if (mode == 2) {
                int which = ncol >> 8, h = (ncol >> 5) & 7, d = ncol & 31;
                int bb = mrow >> 11, ss = mrow & (S_LEN - 1);
                int bhi = (bb << 3) + h;
                _Float16 hv = (_Float16)v;
                if (which == 0)      Qh[((size_t)bhi * S_LEN + ss) * DH + d] = hv;
                else if (which == 1) Kh[((size_t)bhi * S_LEN + ss) * DH + d] = hv;
                else                 Vh[((size_t)bhi * DH + d) * S_LEN + ss] = hv;
            } else {
                Y[(size_t)mrow * N + ncol] = v;
            }
        }
    }
}

// ---------------- MFMA flash attention ----------------
// grid: B*NH*(S/64) blocks of 256 threads; wave w handles 16 query rows.
// Scores: D = K_tile * Q^T via mfma_f32_16x16x32_f16 -> lane holds 4 key-scores
// (keys 4g+r) for query col c. PV: O^T[dh][q] += V^T * P^T via 16x16x16 f16
// (B-frag layout == score D layout, no relayout needed).
__global__ __launch_bounds__(256) void attn_k(
    const _Float16* __restrict__ Qf, const _Float16* __restrict__ Kf,
    const _Float16* __restrict__ Vf, const int* __restrict__ t_all,
    const float* __restrict__ alpha, float* __restrict__ O)
{
    const int bh = blockIdx.x >> 5;           // /(S/64)=32
    const int itile = blockIdx.x & 31;
    const int b = bh >> 3, h = bh & 7;
    const int w = threadIdx.x >> 6;
    const int lane = threadIdx.x & 63;
    const int c = lane & 15, g = lane >> 4;
    const int i0 = (itile << 6) + (w << 4);

    const float LOG2E = 1.44269504088896f;
    const float sc2 = 0.17677669529663687f * LOG2E;
    const float ah2 = alpha[h] * LOG2E;

    const _Float16* Qbh = Qf + (size_t)bh * S_LEN * DH;
    const _Float16* Kbh = Kf + (size_t)bh * S_LEN * DH;
    const _Float16* Vbh = Vf + (size_t)bh * DH * S_LEN;
    const int* tb = t_all + b * S_LEN;

    f16x8 qfrag = *(const f16x8*)(Qbh + (size_t)(i0 + c) * DH + (g << 3));
    const int ti = tb[i0 + c];

    float m2 = -3.0e38f, l = 0.0f;
    f32x4 acc0 = {0.f, 0.f, 0.f, 0.f};
    f32x4 acc1 = {0.f, 0.f, 0.f, 0.f};
    const f32x4 zero = {0.f, 0.f, 0.f, 0.f};

    for (int j0 = 0; j0 < CTX; j0 += 16) {
        f16x8 kfrag = *(const f16x8*)(Kbh + (size_t)(j0 + c) * DH + (g << 3));
        f32x4 d2 = __builtin_amdgcn_mfma_f32_16x16x32_f16(kfrag, qfrag, zero, 0, 0, 0);
        int4 tj = *(const int4*)(tb + j0 + (g << 2));
        float s0 = (tj.x <= ti) ? d2[0] * sc2 - ah2 * (float)(ti - tj.x) : -1e9f;
        float s1 = (tj.y <= ti) ? d2[1] * sc2 - ah2 * (float)(ti - tj.y) : -1e9f;
        float s2 = (tj.z <= ti) ? d2[2] * sc2 - ah2 * (float)(ti - tj.z) : -1e9f;
        float s3 = (tj.w <= ti) ? d2[3] * sc2 - ah2 * (float)(ti - tj.w) : -1e9f;
        float pmax = fmaxf(fmaxf(s0, s1), fmaxf(s2, s3));
        pmax = fmaxf(pmax, __shfl_xor(pmax, 16, 64));
        pmax = fmaxf(pmax, __shfl_xor(pmax, 32, 64));
        float mnew = fmaxf(m2, pmax);
        float f = __builtin_amdgcn_exp2f(m2 - mnew);
        m2 = mnew;
        float p0 = __builtin_amdgcn_exp2f(s0 - m2);
        float p1 = __builtin_amdgcn_exp2f(s1 - m2);
        float p2 = __builtin_amdgcn_exp2f(s2 - m2);
        float p3 = __builtin_amdgcn_exp2f(s3 - m2);
        float ps = (p0 + p1) + (p2 + p3);
        ps += __shfl_xor(ps, 16, 64);
        ps += __shfl_xor(ps, 32, 64);
        l = l * f + ps;
        acc0 *= f;
        acc1 *= f;
        f16x4 pf = {(_Float16)p0, (_Float16)p1, (_Float16)p2, (_Float16)p3};
        f16x4 v0 = *(const f16x4*)(Vbh + (size_t)c * S_LEN + j0 + (g << 2));
        f16x4 v1 = *(const f16x4*)(Vbh + (size_t)(16 + c) * S_LEN + j0 + (g << 2));
        acc0 = __builtin_amdgcn_mfma_f32_16x16x16f16(v0, pf, acc0, 0, 0, 0);
        acc1 = __builtin_amdgcn_mfma_f32_16x16x16f16(v1, pf, acc1, 0, 0, 0);
    }

    // fully-masked rows: reference softmaxes uniformly over ALL keys (masked
    // scores are exactly -1e9). p = exp2(-1e9 - m2) is 1 iff m2==-1e9, else 0.
    if (__any(m2 < -5e8f)) {
        float p0 = __builtin_amdgcn_exp2f(-1e9f - m2);
        _Float16 ph = (_Float16)p0;
        f16x4 pf = {ph, ph, ph, ph};
        for (int j0 = CTX; j0 < S_LEN; j0 += 16) {
            l += 16.0f * p0;
            f16x4 v0 = *(const f16x4*)(Vbh + (size_t)c * S_LEN + j0 + (g << 2));
            f16x4 v1 = *(const f16x4*)(Vbh + (size_t)(16 + c) * S_LEN + j0 + (g << 2));
            acc0 = __builtin_amdgcn_mfma_f32_16x16x16f16(v0, pf, acc0, 0, 0, 0);
            acc1 = __builtin_amdgcn_mfma_f32_16x16x16f16(v1, pf, acc1, 0, 0, 0);
        }
    }

    float inv = 1.0f / l;
    float* Orow = O + ((size_t)(b * S_LEN) + i0 + c) * DD + h * DH;
    float4 o0 = make_float4(acc0[0] * inv, acc0[1] * inv, acc0[2] * inv, acc0[3] * inv);
    float4 o1 = make_float4(acc1[0] * inv, acc1[1] * inv, acc1[2] * inv, acc1[3] * inv);
    *(float4*)(Orow + (g << 2)) = o0;
    *(float4*)(Orow + 16 + (g << 2)) = o1;
}

// ---------------- Residual + LayerNorm (in-place on Z) ----------------
__global__ __launch_bounds__(256) void ln_k(
    float* __restrict__ Z, const float* __restrict__ Y,
    const float* __restrict__ sw, const float* __restrict__ bw)
{
    int row = blockIdx.x, t = threadIdx.x;
    float x = Z[(size_t)row * DD + t] + Y[(size_t)row * DD + t];
    float s1 = x, s2 = x * x;
    #pragma unroll
    for (int off = 32; off > 0; off >>= 1) {
        s1 += __shfl_xor(s1, off, 64);
        s2 += __shfl_xor(s2, off, 64);
    }
    __shared__ float ps1[4], ps2[4];
    int w = t >> 6, lane = t & 63;
    if (lane == 0) { ps1[w] = s1; ps2[w] = s2; }
    __syncthreads();
    float S1 = ps1[0] + ps1[1] + ps1[2] + ps1[3];
    float S2 = ps2[0] + ps2[1] + ps2[2] + ps2[3];
    float mu = S1 * (1.0f / DD);
    float var = S2 * (1.0f / DD) - mu * mu;
    float rs = rsqrtf(var + 1e-5f);
    Z[(size_t)row * DD + t] = (x - mu) * rs * sw[t] + bw[t];
}

// ---------------- Output head ----------------
__global__ __launch_bounds__(256) void outhead_k(
    const float* __restrict__ Z, const float* __restrict__ Wout,
    const float* __restrict__ bout, float* __restrict__ out)
{
    int tid = threadIdx.x;
    int rloc = tid >> 4, ho = tid & 15;
    int qrow = blockIdx.x * 16 + rloc;     // 0..1023
    int b = qrow >> 9, qi = qrow & (QQ - 1);
    if (ho < HOUTD) {
        const float* z = Z + (size_t)(b * S_LEN + CTX + qi) * DD;
        const float* wr = Wout + (size_t)ho * DD;
        float s = 0.0f;
        for (int d = 0; d < DD; d++) s += z[d] * wr[d];
        out[(size_t)(b * QQ + qi) * HOUTD + ho] = s + bout[ho];
    }
}

extern "C" void kernel_launch(void* const* d_in, const int* in_sizes, int n_in,
                              void* d_out, int out_size, void* d_ws, size_t ws_size,
                              hipStream_t stream) {
    (void)in_sizes; (void)n_in; (void)out_size; (void)ws_size;
    const float* ctx_x = (const float*)d_in[0];
    const float* ctx_z = (const float*)d_in[1];
    const float* qry_x = (const float*)d_in[2];
    const int* t_ctx = (const int*)d_in[3];
    const int* t_qry = (const int*)d_in[4];
    const float* W_ctx = (const float*)d_in[5];
    const float* b_ctx = (const float*)d_in[6];
    const float* W_qry = (const float*)d_in[7];
    const float* b_qry = (const float*)d_in[8];
    const float* alpha = (const float*)d_in[9];
    const float* Wqkv = (const float*)d_in[10];
    const float* bqkv = (const float*)d_in[11];
    const float* Wo = (const float*)d_in[12];
    const float* bo = (const float*)d_in[13];
    const float* ln1_s = (const float*)d_in[14];
    const float* ln1_b = (const float*)d_in[15];
    const float* W1 = (const float*)d_in[16];
    const float* b1 = (const float*)d_in[17];
    const float* W2 = (const float*)d_in[18];
    const float* b2 = (const float*)d_in[19];
    const float* ln2_s = (const float*)d_in[20];
    const float* ln2_b = (const float*)d_in[21];
    const float* W_out = (const float*)d_in[22];
    const float* b_out = (const float*)d_in[23];

    float* ws = (float*)d_ws;
    const size_t MTOT = (size_t)BB * S_LEN;       // 4096
    const size_t ZSZ = MTOT * DD;                 // 1M floats
    float* Z   = ws;                              // [0, 1M)
    float* AY  = ws + ZSZ;                        // [1M, 2M)
    float* Yb  = ws + 2 * ZSZ;                    // [2M, 3M)
    float* FF1 = ws + 3 * ZSZ;                    // [3M, 7M)
    int*   t_all = (int*)(ws + 7 * ZSZ);          // 4096 ints
    _Float16* Qh = (_Float16*)(ws + 7 * ZSZ + 4096);
    const size_t HSZ = (size_t)BB * NH * S_LEN * DH;   // 1M halfs
    _Float16* Kh = Qh + HSZ;
    _Float16* Vh = Qh + 2 * HSZ;

    tall_k<<<MTOT / 256, 256, 0, stream>>>(t_ctx, t_qry, t_all);
    embed_k<<<MTOT, 256, 0, stream>>>(ctx_x, ctx_z, qry_x, W_ctx, b_ctx, W_qry, b_qry, Z);

    for (int l = 0; l < NL; l++) {
        gemm_k<<<dim3(MTOT / 64, (3 * DD) / 64), 256, 0, stream>>>(
            Z, Wqkv + (size_t)l * 3 * DD * DD, bqkv + (size_t)l * 3 * DD, nullptr,
            (int)MTOT, 3 * DD, DD, 2, Qh, Kh, Vh);
        attn_k<<<BB * NH * (S_LEN / 64), 256, 0, stream>>>(
            Qh, Kh, Vh, t_all, alpha, AY);
        gemm_k<<<dim3(MTOT / 64, DD / 64), 256, 0, stream>>>(
            AY, Wo + (size_t)l * DD * DD, bo + (size_t)l * DD, Yb,
            (int)MTOT, DD, DD, 0, nullptr, nullptr, nullptr);
        ln_k<<<MTOT, 256, 0, stream>>>(Z, Yb, ln1_s + (size_t)l * DD, ln1_b + (size_t)l * DD);
        gemm_k<<<dim3(MTOT / 64, DFF / 64), 256, 0, stream>>>(
            Z, W1 + (size_t)l * DFF * DD, b1 + (size_t)l * DFF, FF1,
            (int)MTOT, DFF, DD, 1, nullptr, nullptr, nullptr);
        gemm_k<<<dim3(MTOT / 64, DD / 64), 256, 0, stream>>>(
            FF1, W2 + (size_t)l * DD * DFF, b2 + (size_t)l * DD, Yb,
            (int)MTOT, DD, DFF, 0, nullptr, nullptr, nullptr);
        ln_k<<<MTOT, 256, 0, stream>>>(Z, Yb, ln2_s + (size_t)l * DD, ln2_b + (size_t)l * DD);
    }

    outhead_k<<<(BB * QQ) / 16, 256, 0, stream>>>(Z, W_out, b_out, (float*)d_out);
}

// Round 3
// 687.271 us; speedup vs baseline: 6.6240x; 1.7899x over previous
//
#include <hip/hip_runtime.h>
#include <hip/hip_bf16.h>
#include <cstddef>

#define BB   2
#define CTX  1536
#define QQ   512
#define S_LEN 2048
#define DD   256
#define NH   8
#define DH   32
#define DFF  1024
#define NL   6
#define LIN  20
#define HOUTD 10

typedef _Float16 f16x4 __attribute__((ext_vector_type(4)));
typedef _Float16 f16x8 __attribute__((ext_vector_type(8)));
typedef float f32x4 __attribute__((ext_vector_type(4)));

// ---------------- fp32 -> f16 convert (weights) ----------------
__global__ __launch_bounds__(256) void cvt_k(
    const float* __restrict__ src, _Float16* __restrict__ dst, int n4)
{
    int i = blockIdx.x * 256 + threadIdx.x;
    if (i < n4) {
        float4 v = ((const float4*)src)[i];
        f16x4 h = {(_Float16)v.x, (_Float16)v.y, (_Float16)v.z, (_Float16)v.w};
        ((f16x4*)dst)[i] = h;
    }
}

// ---------------- t_all concat ----------------
__global__ __launch_bounds__(256) void tall_k(
    const int* __restrict__ t_ctx, const int* __restrict__ t_qry, int* __restrict__ t_all)
{
    int idx = blockIdx.x * 256 + threadIdx.x;     // 0..4095
    int b = idx >> 11, s = idx & (S_LEN - 1);
    t_all[idx] = (s < CTX) ? t_ctx[b * CTX + s] : t_qry[b * QQ + s - CTX];
}

// ---------------- Embed: Z[b*S+s][d] (+f16 copy) ----------------
__global__ __launch_bounds__(256) void embed_k(
    const float* __restrict__ ctx_x, const float* __restrict__ ctx_z,
    const float* __restrict__ qry_x,
    const float* __restrict__ W_ctx, const float* __restrict__ b_ctx,
    const float* __restrict__ W_qry, const float* __restrict__ b_qry,
    float* __restrict__ Z, _Float16* __restrict__ Zh)
{
    int row = blockIdx.x;            // 0..4095
    int d = threadIdx.x;             // 0..255
    int b = row >> 11, s = row & (S_LEN - 1);
    float acc;
    if (s < CTX) {
        const float* x1 = ctx_x + (size_t)(b * CTX + s) * LIN;
        const float* x2 = ctx_z + (size_t)(b * CTX + s) * HOUTD;
        const float* w = W_ctx + (size_t)d * (LIN + HOUTD);
        acc = b_ctx[d];
        #pragma unroll
        for (int i = 0; i < LIN; i++) acc += x1[i] * w[i];
        #pragma unroll
        for (int i = 0; i < HOUTD; i++) acc += x2[i] * w[LIN + i];
    } else {
        int qi = s - CTX;
        const float* x1 = qry_x + (size_t)(b * QQ + qi) * LIN;
        const float* w = W_qry + (size_t)d * (LIN + HOUTD);
        acc = b_qry[d];
        #pragma unroll
        for (int i = 0; i < LIN; i++) acc += x1[i] * w[i];
    }
    Z[(size_t)row * DD + d] = acc;
    Zh[(size_t)row * DD + d] = (_Float16)acc;
}

// ---------------- MFMA f16 GEMM: Y[M,N] = Xh[M,K] @ Wh[N,K]^T + bias ----------------
// mode 0: fp32 out Y   mode 1: relu -> f16 Yh   mode 2: f16 Q,K:[B,NH,S,DH] V:[B,NH,DH,S]
__global__ __launch_bounds__(256) void hgemm_k(
    const _Float16* __restrict__ X, const _Float16* __restrict__ W,
    const float* __restrict__ bias, float* __restrict__ Y,
    _Float16* __restrict__ Yh, int M, int N, int K, int mode,
    _Float16* __restrict__ Qh, _Float16* __restrict__ Kh, _Float16* __restrict__ Vh)
{
    __shared__ _Float16 Ah[64][32];
    __shared__ _Float16 Bh[64][32];
    const int tid = threadIdx.x;
    const int bm = blockIdx.x << 6, bn = blockIdx.y << 6;
    const int lr = tid >> 2;            // 0..63 (tile row)
    const int lk = (tid & 3) << 3;      // 0,8,16,24 (k chunk)
    const int w = tid >> 6, lane = tid & 63;
    const int c = lane & 15, g = lane >> 4;
    const int wm = (w >> 1) << 5, wn = (w & 1) << 5;

    f32x4 acc00 = {0.f,0.f,0.f,0.f}, acc01 = {0.f,0.f,0.f,0.f};
    f32x4 acc10 = {0.f,0.f,0.f,0.f}, acc11 = {0.f,0.f,0.f,0.f};

    const _Float16* Xp = X + (size_t)(bm + lr) * K + lk;
    const _Float16* Wp = W + (size_t)(bn + lr) * K + lk;

    f16x8 xa = *(const f16x8*)Xp;
    f16x8 wb = *(const f16x8*)Wp;
    const int nt = K >> 5;
    for (int t = 0; t < nt; t++) {
        __syncthreads();
        *(f16x8*)&Ah[lr][lk] = xa;
        *(f16x8*)&Bh[lr][lk] = wb;
        __syncthreads();
        if (t + 1 < nt) {
            xa = *(const f16x8*)(Xp + ((size_t)(t + 1) << 5));
            wb = *(const f16x8*)(Wp + ((size_t)(t + 1) << 5));
        }
        f16x8 a0 = *(const f16x8*)&Ah[wm + c][g << 3];
        f16x8 a1 = *(const f16x8*)&Ah[wm + 16 + c][g << 3];
        f16x8 b0 = *(const f16x8*)&Bh[wn + c][g << 3];
        f16x8 b1 = *(const f16x8*)&Bh[wn + 16 + c][g << 3];
        acc00 = __builtin_amdgcn_mfma_f32_16x16x32_f16(a0, b0, acc00, 0, 0, 0);
        acc01 = __builtin_amdgcn_mfma_f32_16x16x32_f16(a0, b1, acc01, 0, 0, 0);
        acc10 = __builtin_amdgcn_mfma_f32_16x16x32_f16(a1, b0, acc10, 0, 0, 0);
        acc11 = __builtin_amdgcn_mfma_f32_16x16x32_f16(a1, b1, acc11, 0, 0, 0);
    }

    f32x4 accs[2][2] = {{acc00, acc01}, {acc10, acc11}};
    #pragma unroll
    for (int fm = 0; fm < 2; fm++) {
        #pragma unroll
        for (int fn = 0; fn < 2; fn++) {
            int colb = bn + wn + (fn << 4) + c;
            float bv = bias[colb];
            #pragma unroll
            for (int r = 0; r < 4; r++) {
                int row = bm + wm + (fm << 4) + (g << 2) + r;
                float v = accs[fm][fn][r] + bv;
                if (mode == 0) {
                    Y[(size_t)row * N + colb] = v;
                } else if (mode == 1) {
                    Yh[(size_t)row * N + colb] = (_Float16)fmaxf(v, 0.0f);
                } else {
                    int which = colb >> 8, h = (colb >> 5) & 7, d = colb & 31;
                    int bb2 = row >> 11, ss = row & (S_LEN - 1);
                    int bhi = (bb2 << 3) + h;
                    _Float16 hv = (_Float16)v;
                    if (which == 0)      Qh[((size_t)bhi * S_LEN + ss) * DH + d] = hv;
                    else if (which == 1) Kh[((size_t)bhi * S_LEN + ss) * DH + d] = hv;
                    else                 Vh[((size_t)bhi * DH + d) * S_LEN + ss] = hv;
                }
            }
        }
    }
}

// ---------------- MFMA flash attention (32-key steps, skip-rescale) ----------------
__global__ __launch_bounds__(256) void attn_k(
    const _Float16* __restrict__ Qf, const _Float16* __restrict__ Kf,
    const _Float16* __restrict__ Vf, const int* __restrict__ t_all,
    const float* __restrict__ alpha, _Float16* __restrict__ O)
{
    const int bh = blockIdx.x >> 5;           // /(S/64)=32
    const int itile = blockIdx.x & 31;
    const int b = bh >> 3, h = bh & 7;
    const int w = threadIdx.x >> 6;
    const int lane = threadIdx.x & 63;
    const int c = lane & 15, g = lane >> 4;
    const int i0 = (itile << 6) + (w << 4);

    const float LOG2E = 1.44269504088896f;
    const float sc2 = 0.17677669529663687f * LOG2E;
    const float ah2 = alpha[h] * LOG2E;

    const _Float16* Qbh = Qf + (size_t)bh * S_LEN * DH;
    const _Float16* Kbh = Kf + (size_t)bh * S_LEN * DH;
    const _Float16* Vbh = Vf + (size_t)bh * DH * S_LEN;
    const int* tb = t_all + b * S_LEN;

    f16x8 qfrag = *(const f16x8*)(Qbh + (size_t)(i0 + c) * DH + (g << 3));
    const int ti = tb[i0 + c];

    float m2 = -3.0e38f, l = 0.0f;
    f32x4 acc0 = {0.f, 0.f, 0.f, 0.f};
    f32x4 acc1 = {0.f, 0.f, 0.f, 0.f};
    const f32x4 zero = {0.f, 0.f, 0.f, 0.f};

    for (int j0 = 0; j0 < CTX; j0 += 32) {
        f16x8 kf0 = *(const f16x8*)(Kbh + (size_t)(j0 + c) * DH + (g << 3));
        f16x8 kf1 = *(const f16x8*)(Kbh + (size_t)(j0 + 16 + c) * DH + (g << 3));
        f32x4 dA = __builtin_amdgcn_mfma_f32_16x16x32_f16(kf0, qfrag, zero, 0, 0, 0);
        f32x4 dB = __builtin_amdgcn_mfma_f32_16x16x32_f16(kf1, qfrag, zero, 0, 0, 0);
        int4 tjA = *(const int4*)(tb + j0 + (g << 2));
        int4 tjB = *(const int4*)(tb + j0 + 16 + (g << 2));
        float sA0 = (tjA.x <= ti) ? dA[0] * sc2 - ah2 * (float)(ti - tjA.x) : -1e9f;
        float sA1 = (tjA.y <= ti) ? dA[1] * sc2 - ah2 * (float)(ti - tjA.y) : -1e9f;
        float sA2 = (tjA.z <= ti) ? dA[2] * sc2 - ah2 * (float)(ti - tjA.z) : -1e9f;
        float sA3 = (tjA.w <= ti) ? dA[3] * sc2 - ah2 * (float)(ti - tjA.w) : -1e9f;
        float sB0 = (tjB.x <= ti) ? dB[0] * sc2 - ah2 * (float)(ti - tjB.x) : -1e9f;
        float sB1 = (tjB.y <= ti) ? dB[1] * sc2 - ah2 * (float)(ti - tjB.y) : -1e9f;
        float sB2 = (tjB.z <= ti) ? dB[2] * sc2 - ah2 * (float)(ti - tjB.z) : -1e9f;
        float sB3 = (tjB.w <= ti) ? dB[3] * sc2 - ah2 * (float)(ti - tjB.w) : -1e9f;
        float pmax = fmaxf(fmaxf(fmaxf(sA0, sA1), fmaxf(sA2, sA3)),
                           fmaxf(fmaxf(sB0, sB1), fmaxf(sB2, sB3)));
        pmax = fmaxf(pmax, __shfl_xor(pmax, 16, 64));
        pmax = fmaxf(pmax, __shfl_xor(pmax, 32, 64));
        if (__any(pmax > m2)) {
            float mnew = fmaxf(m2, pmax);
            float f = __builtin_amdgcn_exp2f(m2 - mnew);
            m2 = mnew;
            l *= f; acc0 *= f; acc1 *= f;
        }
        float pA0 = __builtin_amdgcn_exp2f(sA0 - m2);
        float pA1 = __builtin_amdgcn_exp2f(sA1 - m2);
        float pA2 = __builtin_amdgcn_exp2f(sA2 - m2);
        float pA3 = __builtin_amdgcn_exp2f(sA3 - m2);
        float pB0 = __builtin_amdgcn_exp2f(sB0 - m2);
        float pB1 = __builtin_amdgcn_exp2f(sB1 - m2);
        float pB2 = __builtin_amdgcn_exp2f(sB2 - m2);
        float pB3 = __builtin_amdgcn_exp2f(sB3 - m2);
        float ps = ((pA0 + pA1) + (pA2 + pA3)) + ((pB0 + pB1) + (pB2 + pB3));
        ps += __shfl_xor(ps, 16, 64);
        ps += __shfl_xor(ps, 32, 64);
        l += ps;
        f16x4 pfA = {(_Float16)pA0, (_Float16)pA1, (_Float16)pA2, (_Float16)pA3};
        f16x4 pfB = {(_Float16)pB0, (_Float16)pB1, (_Float16)pB2, (_Float16)pB3};
        f16x4 vA0 = *(const f16x4*)(Vbh + (size_t)c * S_LEN + j0 + (g << 2));
        f16x4 vA1 = *(const f16x4*)(Vbh + (size_t)(16 + c) * S_LEN + j0 + (g << 2));
        f16x4 vB0 = *(const f16x4*)(Vbh + (size_t)c * S_LEN + j0 + 16 + (g << 2));
        f16x4 vB1 = *(const f16x4*)(Vbh + (size_t)(16 + c) * S_LEN + j0 + 16 + (g << 2));
        acc0 = __builtin_amdgcn_mfma_f32_16x16x16f16(vA0, pfA, acc0, 0, 0, 0);
        acc0 = __builtin_amdgcn_mfma_f32_16x16x16f16(vB0, pfB, acc0, 0, 0, 0);
        acc1 = __builtin_amdgcn_mfma_f32_16x16x16f16(vA1, pfA, acc1, 0, 0, 0);
        acc1 = __builtin_amdgcn_mfma_f32_16x16x16f16(vB1, pfB, acc1, 0, 0, 0);
    }

    // fully-masked rows: reference softmaxes uniformly over ALL keys.
    if (__any(m2 < -5e8f)) {
        float p0 = __builtin_amdgcn_exp2f(-1e9f - m2);
        _Float16 ph = (_Float16)p0;
        f16x4 pf = {ph, ph, ph, ph};
        for (int j0 = CTX; j0 < S_LEN; j0 += 16) {
            l += 16.0f * p0;
            f16x4 v0 = *(const f16x4*)(Vbh + (size_t)c * S_LEN + j0 + (g << 2));
            f16x4 v1 = *(const f16x4*)(Vbh + (size_t)(16 + c) * S_LEN + j0 + (g << 2));
            acc0 = __builtin_amdgcn_mfma_f32_16x16x16f16(v0, pf, acc0, 0, 0, 0);
            acc1 = __builtin_amdgcn_mfma_f32_16x16x16f16(v1, pf, acc1, 0, 0, 0);
        }
    }

    float inv = 1.0f / l;
    _Float16* Orow = O + ((size_t)(b * S_LEN) + i0 + c) * DD + h * DH;
    f16x4 o0 = {(_Float16)(acc0[0]*inv), (_Float16)(acc0[1]*inv), (_Float16)(acc0[2]*inv), (_Float16)(acc0[3]*inv)};
    f16x4 o1 = {(_Float16)(acc1[0]*inv), (_Float16)(acc1[1]*inv), (_Float16)(acc1[2]*inv), (_Float16)(acc1[3]*inv)};
    *(f16x4*)(Orow + (g << 2)) = o0;
    *(f16x4*)(Orow + 16 + (g << 2)) = o1;
}

// ---------------- Residual + LayerNorm (in-place on Z, +f16 copy) ----------------
__global__ __launch_bounds__(256) void ln_k(
    float* __restrict__ Z, const float* __restrict__ Y,
    const float* __restrict__ sw, const float* __restrict__ bw,
    _Float16* __restrict__ Zh)
{
    int row = blockIdx.x, t = threadIdx.x;
    float x = Z[(size_t)row * DD + t] + Y[(size_t)row * DD + t];
    float s1 = x, s2 = x * x;
    #pragma unroll
    for (int off = 32; off > 0; off >>= 1) {
        s1 += __shfl_xor(s1, off, 64);
        s2 += __shfl_xor(s2, off, 64);
    }
    __shared__ float ps1[4], ps2[4];
    int w = t >> 6, lane = t & 63;
    if (lane == 0) { ps1[w] = s1; ps2[w] = s2; }
    __syncthreads();
    float S1 = ps1[0] + ps1[1] + ps1[2] + ps1[3];
    float S2 = ps2[0] + ps2[1] + ps2[2] + ps2[3];
    float mu = S1 * (1.0f / DD);
    float var = S2 * (1.0f / DD) - mu * mu;
    float rs = rsqrtf(var + 1e-5f);
    float o = (x - mu) * rs * sw[t] + bw[t];
    Z[(size_t)row * DD + t] = o;
    Zh[(size_t)row * DD + t] = (_Float16)o;
}

// ---------------- Output head ----------------
__global__ __launch_bounds__(256) void outhead_k(
    const float* __restrict__ Z, const float* __restrict__ Wout,
    const float* __restrict__ bout, float* __restrict__ out)
{
    int tid = threadIdx.x;
    int rloc = tid >> 4, ho = tid & 15;
    int qrow = blockIdx.x * 16 + rloc;     // 0..1023
    int b = qrow >> 9, qi = qrow & (QQ - 1);
    if (ho < HOUTD) {
        const float* z = Z + (size_t)(b * S_LEN + CTX + qi) * DD;
        const float* wr = Wout + (size_t)ho * DD;
        float s = 0.0f;
        for (int d = 0; d < DD; d++) s += z[d] * wr[d];
        out[(size_t)(b * QQ + qi) * HOUTD + ho] = s + bout[ho];
    }
}

extern "C" void kernel_launch(void* const* d_in, const int* in_sizes, int n_in,
                              void* d_out, int out_size, void* d_ws, size_t ws_size,
                              hipStream_t stream) {
    (void)in_sizes; (void)n_in; (void)out_size; (void)ws_size;
    const float* ctx_x = (const float*)d_in[0];
    const float* ctx_z = (const float*)d_in[1];
    const float* qry_x = (const float*)d_in[2];
    const int* t_ctx = (const int*)d_in[3];
    const int* t_qry = (const int*)d_in[4];
    const float* W_ctx = (const float*)d_in[5];
    const float* b_ctx = (const float*)d_in[6];
    const float* W_qry = (const float*)d_in[7];
    const float* b_qry = (const float*)d_in[8];
    const float* alpha = (const float*)d_in[9];
    const float* Wqkv = (const float*)d_in[10];
    const float* bqkv = (const float*)d_in[11];
    const float* Wo = (const float*)d_in[12];
    const float* bo = (const float*)d_in[13];
    const float* ln1_s = (const float*)d_in[14];
    const float* ln1_b = (const float*)d_in[15];
    const float* W1 = (const float*)d_in[16];
    const float* b1 = (const float*)d_in[17];
    const float* W2 = (const float*)d_in[18];
    const float* b2 = (const float*)d_in[19];
    const float* ln2_s = (const float*)d_in[20];
    const float* ln2_b = (const float*)d_in[21];
    const float* W_out = (const float*)d_in[22];
    const float* b_out = (const float*)d_in[23];

    float* ws = (float*)d_ws;
    const size_t MTOT = (size_t)BB * S_LEN;       // 4096
    const size_t ZSZ = MTOT * DD;                 // 1M floats
    float* Z   = ws;                              // [0, 1M) f
    float* Yb  = ws + ZSZ;                        // [1M, 2M) f
    _Float16* Zh   = (_Float16*)(ws + 2 * ZSZ);          // 1M halfs
    _Float16* AYh  = (_Float16*)(ws + 2 * ZSZ + ZSZ / 2);
    _Float16* FF1h = (_Float16*)(ws + 3 * ZSZ);          // 4M halfs
    _Float16* Qh   = (_Float16*)(ws + 5 * ZSZ);
    _Float16* Kh   = (_Float16*)(ws + 5 * ZSZ + ZSZ / 2);
    _Float16* Vh   = (_Float16*)(ws + 6 * ZSZ);
    int* t_all     = (int*)(ws + 6 * ZSZ + ZSZ / 2);     // 4096 ints
    _Float16* Whqkv = (_Float16*)(ws + 6 * ZSZ + ZSZ / 2 + 4096);
    _Float16* Who   = Whqkv + (size_t)NL * 3 * DD * DD;  // +1,179,648
    _Float16* Wh1   = Who   + (size_t)NL * DD * DD;      // +393,216
    _Float16* Wh2   = Wh1   + (size_t)NL * DFF * DD;     // +1,572,864

    {
        int n4;
        n4 = NL * 3 * DD * DD / 4;
        cvt_k<<<(n4 + 255) / 256, 256, 0, stream>>>(Wqkv, Whqkv, n4);
        n4 = NL * DD * DD / 4;
        cvt_k<<<(n4 + 255) / 256, 256, 0, stream>>>(Wo, Who, n4);
        n4 = NL * DFF * DD / 4;
        cvt_k<<<(n4 + 255) / 256, 256, 0, stream>>>(W1, Wh1, n4);
        n4 = NL * DD * DFF / 4;
        cvt_k<<<(n4 + 255) / 256, 256, 0, stream>>>(W2, Wh2, n4);
    }

    tall_k<<<MTOT / 256, 256, 0, stream>>>(t_ctx, t_qry, t_all);
    embed_k<<<MTOT, 256, 0, stream>>>(ctx_x, ctx_z, qry_x, W_ctx, b_ctx, W_qry, b_qry, Z, Zh);

    for (int l = 0; l < NL; l++) {
        hgemm_k<<<dim3(MTOT / 64, (3 * DD) / 64), 256, 0, stream>>>(
            Zh, Whqkv + (size_t)l * 3 * DD * DD, bqkv + (size_t)l * 3 * DD,
            nullptr, nullptr, (int)MTOT, 3 * DD, DD, 2, Qh, Kh, Vh);
        attn_k<<<BB * NH * (S_LEN / 64), 256, 0, stream>>>(
            Qh, Kh, Vh, t_all, alpha, AYh);
        hgemm_k<<<dim3(MTOT / 64, DD / 64), 256, 0, stream>>>(
            AYh, Who + (size_t)l * DD * DD, bo + (size_t)l * DD,
            Yb, nullptr, (int)MTOT, DD, DD, 0, nullptr, nullptr, nullptr);
        ln_k<<<MTOT, 256, 0, stream>>>(Z, Yb, ln1_s + (size_t)l * DD, ln1_b + (size_t)l * DD, Zh);
        hgemm_k<<<dim3(MTOT / 64, DFF / 64), 256, 0, stream>>>(
            Zh, Wh1 + (size_t)l * DFF * DD, b1 + (size_t)l * DFF,
            nullptr, FF1h, (int)MTOT, DFF, DD, 1, nullptr, nullptr, nullptr);
        hgemm_k<<<dim3(MTOT / 64, DD / 64), 256, 0, stream>>>(
            FF1h, Wh2 + (size_t)l * DD * DFF, b2 + (size_t)l * DD,
            Yb, nullptr, (int)MTOT, DD, DFF, 0, nullptr, nullptr, nullptr);
        ln_k<<<MTOT, 256, 0, stream>>>(Z, Yb, ln2_s + (size_t)l * DD, ln2_b + (size_t)l * DD, Zh);
    }

    outhead_k<<<(BB * QQ) / 16, 256, 0, stream>>>(Z, W_out, b_out, (float*)d_out);
}